// Round 9
// baseline (179.542 us; speedup 1.0000x reference)
//
#include <hip/hip_runtime.h>
#include <math.h>

// Problem constants (B, S, E, WIN) = (8, 2048, 512, 11)
#define B_    8
#define S_    2048
#define E_    512
#define WIN_  11
#define WW    5              // WIN/2
#define F4C   1408           // float4 per W row (5632/4)
#define E4C   128            // float4 per x row (512/4)
#define PSTR  (B_ * WIN_)    // 88 gate logits per s

// ---- DPP wave-sum: 6 VALU ops, zero DS-pipe traffic. Full sum -> lane 63.
template <int CTRL, int RMASK>
__device__ __forceinline__ float dpp_add(float v) {
    int sh = __builtin_amdgcn_update_dpp(0, __float_as_int(v),
                                         CTRL, RMASK, 0xF, true);
    return v + __int_as_float(sh);
}
__device__ __forceinline__ float wave_sum63(float v) {
    v = dpp_add<0x111, 0xF>(v);   // row_shr:1
    v = dpp_add<0x112, 0xF>(v);   // row_shr:2
    v = dpp_add<0x114, 0xF>(v);   // row_shr:4
    v = dpp_add<0x118, 0xF>(v);   // row_shr:8
    v = dpp_add<0x142, 0xA>(v);   // row_bcast:15
    v = dpp_add<0x143, 0xC>(v);   // row_bcast:31 -> lane 63 = full sum
    return v;
}

__device__ __forceinline__ float tanh_fast(float v) {
    const float e = __expf(v + v);
    return 1.f - 2.f / (e + 1.f);
}

// ---------------------------------------------------------------------------
// Barrier-free W-stream: block per s (2048, XCD-swizzled), 256 thr = 4 waves.
// Wave g owns W rows 3g..3g+2 and loads its fragments STRAIGHT INTO VGPRs —
// no LDS staging, no __syncthreads in the stream loop, hence no vmcnt(0)
// drains (the R7/R8 ceiling: every barrier emptied all load queues once per
// chunk -> ~50% HBM duty). The compiler software-pipelines loads across
// wp-iterations (unroll 2); each wave keeps its 6 W + 16 x loads in flight
// continuously. W read exactly once per block; x rows L1/L2-hot (4 waves
// share them within a block, adjacent s on the same XCD reuse 10/11 rows).
// Pad handling hoisted into loop bounds -> branch-free hot loop.
// Epilogue: DPP reduce -> gates (LDS, one barrier) -> sigmoid -> score+tanh.
// ---------------------------------------------------------------------------
__global__ __launch_bounds__(256)
void win_attn_fused(const float* __restrict__ x,
                    const float* __restrict__ W,
                    const float* __restrict__ bias,
                    float* __restrict__ out)
{
    const int bid  = blockIdx.x;
    const int s    = (bid & 7) * (S_ / 8) + (bid >> 3);   // bijective XCD swizzle
    const int tid  = threadIdx.x;
    const int wid  = tid >> 6;      // wave 0..3
    const int lane = tid & 63;

    const float4* __restrict__ X4 = reinterpret_cast<const float4*>(x);
    const float4* __restrict__ Ws = reinterpret_cast<const float4*>(W)
                                    + (size_t)s * (WIN_ * F4C);

    __shared__ float gates[PSTR];   // 352 B — only LDS in the kernel

    const int w0   = wid * 3;                  // first w-row of this wave
    const int wcnt = (wid == 3) ? 2 : 3;       // wave 3 owns rows 9,10

    float acc[B_][3];
    #pragma unroll
    for (int b = 0; b < B_; ++b)
        #pragma unroll
        for (int j = 0; j < 3; ++j) acc[b][j] = 0.f;

    // valid wp range: row = s - 5 + wp in [0, S)
    const int wpLo = (s >= WW) ? 0 : (WW - s);
    const int wpHi = (WIN_ < S_ + WW - s) ? WIN_ : (S_ + WW - s);

    #pragma unroll 2
    for (int wp = wpLo; wp < wpHi; ++wp) {
        const int row = s - WW + wp;

        // this wave's W fragments for chunk wp: straight to VGPRs
        float4 wv[3][2];
        #pragma unroll
        for (int j = 0; j < 3; ++j)
            if (j < wcnt) {                    // wave-uniform guard
                const float4* wr = Ws + (size_t)(w0 + j) * F4C + wp * E4C;
                wv[j][0] = wr[lane];
                wv[j][1] = wr[lane + 64];
            }

        // batches in two halves to bound live x registers (32 VGPR/half)
        #pragma unroll
        for (int half = 0; half < 2; ++half) {
            float4 xv[4][2];
            #pragma unroll
            for (int bb = 0; bb < 4; ++bb) {
                const int b = half * 4 + bb;
                const float4* xr = X4 + ((size_t)b * S_ + row) * E4C;
                xv[bb][0] = xr[lane];
                xv[bb][1] = xr[lane + 64];
            }
            #pragma unroll
            for (int bb = 0; bb < 4; ++bb) {
                const int b = half * 4 + bb;
                #pragma unroll
                for (int j = 0; j < 3; ++j)
                    if (j < wcnt) {
                        float a = acc[b][j];
                        a = fmaf(xv[bb][0].x, wv[j][0].x, a);
                        a = fmaf(xv[bb][0].y, wv[j][0].y, a);
                        a = fmaf(xv[bb][0].z, wv[j][0].z, a);
                        a = fmaf(xv[bb][0].w, wv[j][0].w, a);
                        a = fmaf(xv[bb][1].x, wv[j][1].x, a);
                        a = fmaf(xv[bb][1].y, wv[j][1].y, a);
                        a = fmaf(xv[bb][1].z, wv[j][1].z, a);
                        a = fmaf(xv[bb][1].w, wv[j][1].w, a);
                        acc[b][j] = a;
                    }
            }
        }
    }

    // ---- DPP reduce (VALU only) -> gate logits ----
    #pragma unroll
    for (int b = 0; b < B_; ++b)
        #pragma unroll
        for (int j = 0; j < 3; ++j)
            if (j < wcnt) acc[b][j] = wave_sum63(acc[b][j]);

    if (lane == 63) {
        #pragma unroll
        for (int b = 0; b < B_; ++b)
            #pragma unroll
            for (int j = 0; j < 3; ++j)
                if (j < wcnt) gates[b * WIN_ + w0 + j] = acc[b][j];
    }
    __syncthreads();    // the ONLY barrier

    if (tid < PSTR) {
        const int w = tid % WIN_;
        const float v = gates[tid] + bias[s * WIN_ + w];
        gates[tid] = 1.f / (1.f + __expf(-v));
    }
    __syncthreads();

    // ---- score + tanh (x rows L1/L2-hot from the stream loop) ----
    float4* __restrict__ OUT4 = reinterpret_cast<float4*>(out);
    #pragma unroll
    for (int it = 0; it < 4; ++it) {
        const int i  = tid + (it << 8);   // 0..1023 -> (b, e4)
        const int b  = i >> 7;
        const int e4 = i & 127;
        float4 sc = make_float4(0.f, 0.f, 0.f, 0.f);
        #pragma unroll
        for (int w = 0; w < WIN_; ++w) {
            const int r = s - WW + w;
            if (r >= 0 && r < S_) {
                const float g   = gates[b * WIN_ + w];
                const float4 xv = X4[((size_t)b * S_ + r) * E4C + e4];
                sc.x = fmaf(g, xv.x, sc.x);
                sc.y = fmaf(g, xv.y, sc.y);
                sc.z = fmaf(g, xv.z, sc.z);
                sc.w = fmaf(g, xv.w, sc.w);
            }
        }
        float4 o;
        o.x = tanh_fast(sc.x);
        o.y = tanh_fast(sc.y);
        o.z = tanh_fast(sc.z);
        o.w = tanh_fast(sc.w);
        OUT4[((size_t)b * S_ + s) * E4C + e4] = o;
    }
}

extern "C" void kernel_launch(void* const* d_in, const int* in_sizes, int n_in,
                              void* d_out, int out_size, void* d_ws, size_t ws_size,
                              hipStream_t stream)
{
    const float* x    = (const float*)d_in[0];
    const float* W    = (const float*)d_in[1];
    const float* bias = (const float*)d_in[2];
    float* out        = (float*)d_out;

    win_attn_fused<<<dim3(S_), dim3(256), 0, stream>>>(x, W, bias, out);
}

// Round 10
// 142.958 us; speedup vs baseline: 1.2559x; 1.2559x over previous
//
#include <hip/hip_runtime.h>
#include <math.h>

// Problem constants (B, S, E, WIN) = (8, 2048, 512, 11)
#define B_    8
#define S_    2048
#define E_    512
#define WIN_  11
#define WW    5              // WIN/2
#define F4C   1408           // float4 per W row (5632/4)
#define E4C   128            // float4 per x row (512/4)
#define PSTR  (B_ * WIN_)    // 88 gate logits per s

// ---- DPP wave-sum: 6 VALU ops, zero DS-pipe traffic. Full sum -> lane 63.
template <int CTRL, int RMASK>
__device__ __forceinline__ float dpp_add(float v) {
    int sh = __builtin_amdgcn_update_dpp(0, __float_as_int(v),
                                         CTRL, RMASK, 0xF, true);
    return v + __int_as_float(sh);
}
__device__ __forceinline__ float wave_sum63(float v) {
    v = dpp_add<0x111, 0xF>(v);   // row_shr:1
    v = dpp_add<0x112, 0xF>(v);   // row_shr:2
    v = dpp_add<0x114, 0xF>(v);   // row_shr:4
    v = dpp_add<0x118, 0xF>(v);   // row_shr:8
    v = dpp_add<0x142, 0xA>(v);   // row_bcast:15
    v = dpp_add<0x143, 0xC>(v);   // row_bcast:31 -> lane 63 = full sum
    return v;
}

__device__ __forceinline__ float tanh_fast(float v) {
    const float e = __expf(v + v);
    return 1.f - 2.f / (e + 1.f);
}

// ---------------------------------------------------------------------------
// Fused, x-deduplicated: block per s (2048, XCD-swizzled), 256 thr = 4 waves.
// Per wp-chunk, stage BOTH via global_load_lds (16B):
//   Wbuf: W[s, :, wp*512:(wp+1)*512]  (22.5 KB, read once chip-wide)
//   xbuf: x[:, s-5+wp, :]             (16 KB, read ONCE per block — was 4x,
//         1.44 GB of L3 x-traffic chip-wide rivaling the W HBM stream; this
//         4x de-dup is the R10 lever)
// -> barrier -> waves ds_read both buffers; wave g owns w-rows 3g..3g+2 for
// all 8 batches -> barrier (WAR). DPP reduce -> gates -> score + tanh.
// LDS 38.3 KB -> 4 blocks/CU; ~110 VGPR -> 4 waves/SIMD.
// ---------------------------------------------------------------------------
__global__ __launch_bounds__(256)
void win_attn_fused(const float* __restrict__ x,
                    const float* __restrict__ W,
                    const float* __restrict__ bias,
                    float* __restrict__ out)
{
    const int bid  = blockIdx.x;
    const int s    = (bid & 7) * (S_ / 8) + (bid >> 3);   // bijective XCD swizzle
    const int tid  = threadIdx.x;
    const int wid  = tid >> 6;      // wave 0..3
    const int lane = tid & 63;

    const float4* __restrict__ X4 = reinterpret_cast<const float4*>(x);
    const float4* __restrict__ Ws = reinterpret_cast<const float4*>(W)
                                    + (size_t)s * (WIN_ * F4C);

    __shared__ float4 Wbuf[WIN_ * E4C];   // 22.5 KB: [w][e4] for current wp
    __shared__ float4 xbuf[B_ * E4C];     // 16 KB:   [b][e4] for current row
    __shared__ float gates[PSTR];

    const int w0   = wid * 3;                  // first w-row of this wave
    const int wcnt = (wid == 3) ? 2 : 3;       // wave 3 owns rows 9,10

    float acc[B_][3];
    #pragma unroll
    for (int b = 0; b < B_; ++b)
        #pragma unroll
        for (int j = 0; j < 3; ++j) acc[b][j] = 0.f;

    const int wpLo = (s >= WW) ? 0 : (WW - s);
    const int wpHi = (WIN_ < S_ + WW - s) ? WIN_ : (S_ + WW - s);

    #pragma unroll 1
    for (int wp = wpLo; wp < wpHi; ++wp) {
        const int row = s - WW + wp;      // always valid in [wpLo, wpHi)

        // ---- stage W chunk (1408 f4) + x row (1024 f4) into LDS ----
        #pragma unroll
        for (int j = 0; j < 6; ++j) {
            const int m = j * 256 + tid;          // [0,1536)
            if (j < 5 || wid < 2) {               // wave-uniform guard (m<1408)
                const int w  = m >> 7;
                const int e4 = m & 127;
                const float4* src = Ws + (size_t)w * F4C + wp * E4C + e4;
                __builtin_amdgcn_global_load_lds(
                    (const __attribute__((address_space(1))) void*)src,
                    (__attribute__((address_space(3))) void*)&Wbuf[m],
                    16, 0, 0);
            }
        }
        #pragma unroll
        for (int j = 0; j < 4; ++j) {
            const int m = j * 256 + tid;          // [0,1024): b = m>>7, e4 = m&127
            const int b  = m >> 7;
            const int e4 = m & 127;
            const float4* src = X4 + ((size_t)b * S_ + row) * E4C + e4;
            __builtin_amdgcn_global_load_lds(
                (const __attribute__((address_space(1))) void*)src,
                (__attribute__((address_space(3))) void*)&xbuf[m],
                16, 0, 0);
        }
        __syncthreads();   // staging complete (vmcnt drain)

        // ---- compute: wave's 3 w-rows x all 8 batches, e-slices lane/lane+64
        float4 wv[3][2];
        #pragma unroll
        for (int j = 0; j < 3; ++j)
            if (j < wcnt) {
                wv[j][0] = Wbuf[(w0 + j) * E4C + lane];
                wv[j][1] = Wbuf[(w0 + j) * E4C + lane + 64];
            }

        #pragma unroll
        for (int half = 0; half < 2; ++half) {
            float4 xv[4][2];
            #pragma unroll
            for (int bb = 0; bb < 4; ++bb) {
                const int b = half * 4 + bb;
                xv[bb][0] = xbuf[b * E4C + lane];
                xv[bb][1] = xbuf[b * E4C + lane + 64];
            }
            #pragma unroll
            for (int bb = 0; bb < 4; ++bb) {
                const int b = half * 4 + bb;
                #pragma unroll
                for (int j = 0; j < 3; ++j)
                    if (j < wcnt) {
                        float a = acc[b][j];
                        a = fmaf(xv[bb][0].x, wv[j][0].x, a);
                        a = fmaf(xv[bb][0].y, wv[j][0].y, a);
                        a = fmaf(xv[bb][0].z, wv[j][0].z, a);
                        a = fmaf(xv[bb][0].w, wv[j][0].w, a);
                        a = fmaf(xv[bb][1].x, wv[j][1].x, a);
                        a = fmaf(xv[bb][1].y, wv[j][1].y, a);
                        a = fmaf(xv[bb][1].z, wv[j][1].z, a);
                        a = fmaf(xv[bb][1].w, wv[j][1].w, a);
                        acc[b][j] = a;
                    }
            }
        }
        __syncthreads();   // WAR: all reads done before next chunk stages
    }

    // ---- DPP reduce (VALU only) -> gate logits -> sigmoid ----
    #pragma unroll
    for (int b = 0; b < B_; ++b)
        #pragma unroll
        for (int j = 0; j < 3; ++j)
            if (j < wcnt) acc[b][j] = wave_sum63(acc[b][j]);

    if (lane == 63) {
        #pragma unroll
        for (int b = 0; b < B_; ++b)
            #pragma unroll
            for (int j = 0; j < 3; ++j)
                if (j < wcnt) gates[b * WIN_ + w0 + j] = acc[b][j];
    }
    __syncthreads();

    if (tid < PSTR) {
        const int w = tid % WIN_;
        const float v = gates[tid] + bias[s * WIN_ + w];
        gates[tid] = 1.f / (1.f + __expf(-v));
    }
    __syncthreads();

    // ---- score + tanh (x rows L2/L3-hot from the chunk loop) ----
    float4* __restrict__ OUT4 = reinterpret_cast<float4*>(out);
    #pragma unroll
    for (int it = 0; it < 4; ++it) {
        const int i  = tid + (it << 8);   // 0..1023 -> (b, e4)
        const int b  = i >> 7;
        const int e4 = i & 127;
        float4 sc = make_float4(0.f, 0.f, 0.f, 0.f);
        #pragma unroll
        for (int w = 0; w < WIN_; ++w) {
            const int r = s - WW + w;
            if (r >= 0 && r < S_) {
                const float g   = gates[b * WIN_ + w];
                const float4 xv = X4[((size_t)b * S_ + r) * E4C + e4];
                sc.x = fmaf(g, xv.x, sc.x);
                sc.y = fmaf(g, xv.y, sc.y);
                sc.z = fmaf(g, xv.z, sc.z);
                sc.w = fmaf(g, xv.w, sc.w);
            }
        }
        float4 o;
        o.x = tanh_fast(sc.x);
        o.y = tanh_fast(sc.y);
        o.z = tanh_fast(sc.z);
        o.w = tanh_fast(sc.w);
        OUT4[((size_t)b * S_ + s) * E4C + e4] = o;
    }
}

extern "C" void kernel_launch(void* const* d_in, const int* in_sizes, int n_in,
                              void* d_out, int out_size, void* d_ws, size_t ws_size,
                              hipStream_t stream)
{
    const float* x    = (const float*)d_in[0];
    const float* W    = (const float*)d_in[1];
    const float* bias = (const float*)d_in[2];
    float* out        = (float*)d_out;

    win_attn_fused<<<dim3(S_), dim3(256), 0, stream>>>(x, W, bias, out);
}